// Round 1
// baseline (6000.889 us; speedup 1.0000x reference)
//
#include <hip/hip_runtime.h>
#include <math.h>

#define NROWS 8192
#define DDIM  1024

// ---------------------------------------------------------------------------
// Projection GEMM: C[8192][1024] = X[8192][1024] @ W[1024][1024], fp32.
// 64x64 tile, BK=16, 256 threads, 4x4 micro-tile per thread.
// ---------------------------------------------------------------------------
__global__ __launch_bounds__(256) void proj_gemm(const float* __restrict__ X,
                                                 const float* __restrict__ W,
                                                 float* __restrict__ C) {
    __shared__ float As[16][64];   // As[k][m]  (A tile, transposed)
    __shared__ float Bs[16][64];   // Bs[k][n]

    const int tid = threadIdx.x;
    const int tx = tid & 15;        // 0..15  -> 4 cols
    const int ty = tid >> 4;        // 0..15  -> 4 rows
    const int m0 = blockIdx.y * 64;
    const int n0 = blockIdx.x * 64;

    // staging indices
    const int lm  = tid >> 2;        // 0..63  A row
    const int lk4 = (tid & 3) * 4;   // A k base (float4)
    const int bk  = tid >> 4;        // 0..15  B k
    const int bn4 = (tid & 15) * 4;  // B n base (float4)

    float acc[4][4] = {};

    for (int kb = 0; kb < DDIM; kb += 16) {
        float4 av = *(const float4*)(X + (size_t)(m0 + lm) * DDIM + kb + lk4);
        As[lk4 + 0][lm] = av.x;
        As[lk4 + 1][lm] = av.y;
        As[lk4 + 2][lm] = av.z;
        As[lk4 + 3][lm] = av.w;
        *(float4*)&Bs[bk][bn4] =
            *(const float4*)(W + (size_t)(kb + bk) * DDIM + n0 + bn4);
        __syncthreads();
#pragma unroll
        for (int k = 0; k < 16; ++k) {
            float4 a = *(const float4*)&As[k][ty * 4];
            float4 b = *(const float4*)&Bs[k][tx * 4];
            float aa[4] = {a.x, a.y, a.z, a.w};
            float bb[4] = {b.x, b.y, b.z, b.w};
#pragma unroll
            for (int i = 0; i < 4; ++i)
#pragma unroll
                for (int j = 0; j < 4; ++j) acc[i][j] += aa[i] * bb[j];
        }
        __syncthreads();
    }
#pragma unroll
    for (int i = 0; i < 4; ++i) {
        float4 v = make_float4(acc[i][0], acc[i][1], acc[i][2], acc[i][3]);
        *(float4*)(C + (size_t)(m0 + ty * 4 + i) * DDIM + n0 + tx * 4) = v;
    }
}

// ---------------------------------------------------------------------------
// Flash-style fused attention, fp32.
//   Out[q, :] = sum_j softmax_j( (Q[q,:].K[j,:]) / 32 ) * X[j, :]
// BM=32 Q-rows/block, BN=128 K-rows/j-tile, KC=128 k-chunk, 512 threads.
// Thread (rr = tid>>6 in 0..7, cc = tid&63):
//   S ownership: rows rr*4+i (i<4), cols {cc, cc+64}
//   O ownership: rows rr*4+i, d = d4*256 + cc*4 + e  (d4<4, e<4)
// ---------------------------------------------------------------------------
constexpr int BM = 32;
constexpr int BN = 128;
constexpr int KC = 128;
constexpr int CR = 16;   // X rows staged per PV chunk

__global__ __launch_bounds__(512) void flash_attn(const float* __restrict__ Qm,
                                                  const float* __restrict__ Km,
                                                  const float* __restrict__ Xm,
                                                  float* __restrict__ Out) {
    __shared__ float Qs[BM * KC];          // 16 KB
    __shared__ float KXs[BN * KC];         // 64 KB: Ks[128][128] / Xs[16][1024]
    __shared__ float Ps[BM][BN + 1];       // ~16.1 KB

    const int tid = threadIdx.x;
    const int cc = tid & 63;
    const int rr = tid >> 6;
    const int q0 = blockIdx.x * BM;

    float O[4][16];
    float m_run[4], l_run[4];
#pragma unroll
    for (int i = 0; i < 4; ++i) {
        m_run[i] = -3.0e38f;
        l_run[i] = 0.0f;
#pragma unroll
        for (int d = 0; d < 16; ++d) O[i][d] = 0.0f;
    }

    // staging thread->element maps
    const int qrow = tid >> 4, qc4 = tid & 15;   // Q tile: 32 rows x 32 slots
    const int krow = tid >> 2, kc4 = tid & 3;    // K tile: 128 rows x 32 slots
    const int xrow = tid >> 5, xc4 = tid & 31;   // X tile: 16 rows x 256 slots
    const int ksw = krow & 7;

    for (int k0 = 0; k0 < NROWS; k0 += BN) {
        float s[4][2] = {};
        // ---- S = Q . K^T over D in KC chunks ----
        for (int kc = 0; kc < DDIM; kc += KC) {
            {   // stage Q (linear; inner reads are wave-broadcast)
                const float4* src =
                    (const float4*)(Qm + (size_t)(q0 + qrow) * DDIM + kc);
                float4* dst = (float4*)(Qs + qrow * KC);
                dst[qc4]      = src[qc4];
                dst[qc4 + 16] = src[qc4 + 16];
            }
            {   // stage K swizzled (T2: lanes read different rows, same cols)
                const float4* src =
                    (const float4*)(Km + (size_t)(k0 + krow) * DDIM + kc);
                float4* dst = (float4*)(KXs + krow * KC);
#pragma unroll
                for (int i = 0; i < 8; ++i) {
                    int slot = kc4 + 4 * i;
                    dst[slot ^ ksw] = src[slot];
                }
            }
            __syncthreads();

            const float4* qp0 = (const float4*)(Qs + (rr * 4 + 0) * KC);
            const float4* qp1 = (const float4*)(Qs + (rr * 4 + 1) * KC);
            const float4* qp2 = (const float4*)(Qs + (rr * 4 + 2) * KC);
            const float4* qp3 = (const float4*)(Qs + (rr * 4 + 3) * KC);
            const float4* kp0 = (const float4*)(KXs + cc * KC);
            const float4* kp1 = (const float4*)(KXs + (cc + 64) * KC);
            const int sw = cc & 7;   // (cc+64)&7 == cc&7

#pragma unroll 8
            for (int t4 = 0; t4 < KC / 4; ++t4) {
                float4 kv0 = kp0[t4 ^ sw];
                float4 kv1 = kp1[t4 ^ sw];
                float4 qv;
                qv = qp0[t4];
                s[0][0] += qv.x * kv0.x + qv.y * kv0.y + qv.z * kv0.z + qv.w * kv0.w;
                s[0][1] += qv.x * kv1.x + qv.y * kv1.y + qv.z * kv1.z + qv.w * kv1.w;
                qv = qp1[t4];
                s[1][0] += qv.x * kv0.x + qv.y * kv0.y + qv.z * kv0.z + qv.w * kv0.w;
                s[1][1] += qv.x * kv1.x + qv.y * kv1.y + qv.z * kv1.z + qv.w * kv1.w;
                qv = qp2[t4];
                s[2][0] += qv.x * kv0.x + qv.y * kv0.y + qv.z * kv0.z + qv.w * kv0.w;
                s[2][1] += qv.x * kv1.x + qv.y * kv1.y + qv.z * kv1.z + qv.w * kv1.w;
                qv = qp3[t4];
                s[3][0] += qv.x * kv0.x + qv.y * kv0.y + qv.z * kv0.z + qv.w * kv0.w;
                s[3][1] += qv.x * kv1.x + qv.y * kv1.y + qv.z * kv1.z + qv.w * kv1.w;
            }
            __syncthreads();
        }

        // ---- online softmax over this j-tile ----
        const float SCALE = 0.03125f;  // 1/sqrt(1024)
#pragma unroll
        for (int i = 0; i < 4; ++i) {
            float s0 = s[i][0] * SCALE;
            float s1 = s[i][1] * SCALE;
            float tm = fmaxf(s0, s1);
#pragma unroll
            for (int off = 32; off >= 1; off >>= 1)
                tm = fmaxf(tm, __shfl_xor(tm, off, 64));
            float mn = fmaxf(m_run[i], tm);
            float p0 = __expf(s0 - mn);
            float p1 = __expf(s1 - mn);
            float ts = p0 + p1;
#pragma unroll
            for (int off = 32; off >= 1; off >>= 1)
                ts += __shfl_xor(ts, off, 64);
            float corr = __expf(m_run[i] - mn);
            l_run[i] = l_run[i] * corr + ts;
            m_run[i] = mn;
#pragma unroll
            for (int d = 0; d < 16; ++d) O[i][d] *= corr;
            Ps[rr * 4 + i][cc]      = p0;
            Ps[rr * 4 + i][cc + 64] = p1;
        }
        __syncthreads();   // Ps visible; all Ks reads done before Xs overwrite

        // ---- O += P . X, X staged CR rows at a time ----
        for (int ch = 0; ch < BN; ch += CR) {
            {   // stage X rows [k0+ch, k0+ch+CR), linear layout
                const float4* src =
                    (const float4*)(Xm + (size_t)(k0 + ch + xrow) * DDIM);
                float4* dst = (float4*)(KXs + xrow * DDIM);
#pragma unroll
                for (int i = 0; i < 8; ++i) {
                    int slot = xc4 + 32 * i;
                    dst[slot] = src[slot];
                }
            }
            __syncthreads();
#pragma unroll 4
            for (int c = 0; c < CR; ++c) {
                float p[4];
#pragma unroll
                for (int i = 0; i < 4; ++i) p[i] = Ps[rr * 4 + i][ch + c];
                const float4* xs = (const float4*)(KXs + c * DDIM);
#pragma unroll
                for (int d4 = 0; d4 < 4; ++d4) {
                    float4 xv = xs[d4 * 64 + cc];   // lane-consecutive 16B
#pragma unroll
                    for (int i = 0; i < 4; ++i) {
                        O[i][d4 * 4 + 0] += p[i] * xv.x;
                        O[i][d4 * 4 + 1] += p[i] * xv.y;
                        O[i][d4 * 4 + 2] += p[i] * xv.z;
                        O[i][d4 * 4 + 3] += p[i] * xv.w;
                    }
                }
            }
            __syncthreads();
        }
    }

    // ---- epilogue: normalize and store (fully coalesced) ----
#pragma unroll
    for (int i = 0; i < 4; ++i) {
        float inv = 1.0f / l_run[i];
        float* orow = Out + (size_t)(q0 + rr * 4 + i) * DDIM;
#pragma unroll
        for (int d4 = 0; d4 < 4; ++d4) {
            float4 v = make_float4(O[i][d4 * 4 + 0] * inv, O[i][d4 * 4 + 1] * inv,
                                   O[i][d4 * 4 + 2] * inv, O[i][d4 * 4 + 3] * inv);
            *(float4*)(orow + d4 * 256 + cc * 4) = v;
        }
    }
}

extern "C" void kernel_launch(void* const* d_in, const int* in_sizes, int n_in,
                              void* d_out, int out_size, void* d_ws, size_t ws_size,
                              hipStream_t stream) {
    const float* X  = (const float*)d_in[0];
    const float* Wq = (const float*)d_in[1];
    const float* Wk = (const float*)d_in[2];
    float* Outp = (float*)d_out;

    // Q lives in d_out (each flash block reads only its own 32 rows of Q and
    // overwrites them only in its epilogue — no cross-block aliasing).
    // K lives in workspace (8192*1024*4 = 33.5 MB).
    float* Qb = Outp;
    float* Kb = (float*)d_ws;

    dim3 pgrid(DDIM / 64, NROWS / 64);   // (16, 128)
    proj_gemm<<<pgrid, 256, 0, stream>>>(X, Wq, Qb);
    proj_gemm<<<pgrid, 256, 0, stream>>>(X, Wk, Kb);

    flash_attn<<<NROWS / BM, 512, 0, stream>>>(Qb, Kb, X, Outp);
}

// Round 2
// 2132.548 us; speedup vs baseline: 2.8140x; 2.8140x over previous
//
#include <hip/hip_runtime.h>
#include <hip/hip_bf16.h>
#include <math.h>

#define NR 8192
#define DD 1024

typedef __attribute__((ext_vector_type(8))) short bf16x8;
typedef __attribute__((ext_vector_type(4))) float f32x4;

struct u16x4 { unsigned short x, y, z, w; };

__device__ __forceinline__ unsigned short f2bf(float v) {
    __hip_bfloat16 h = __float2bfloat16(v);
    return *(unsigned short*)&h;
}
__device__ __forceinline__ float bf2f(unsigned short u) {
    __hip_bfloat16 h = *(__hip_bfloat16*)&u;
    return __bfloat162float(h);
}

// ---------------------------------------------------------------------------
// Projection GEMM: C[8192][1024] = X @ W, fp32 accumulate.
// Epilogue MODE 0: pack per-row records [hi(2048B)|lo(2048B)] into qpack.
// Epilogue MODE 1: write khi/klo bf16 arrays.
// ---------------------------------------------------------------------------
template <int MODE>
__global__ __launch_bounds__(256) void proj_gemm(const float* __restrict__ X,
                                                 const float* __restrict__ W,
                                                 char* qpack,
                                                 unsigned short* khi,
                                                 unsigned short* klo) {
    __shared__ float As[16][64];
    __shared__ float Bs[16][64];

    const int tid = threadIdx.x;
    const int tx = tid & 15;
    const int ty = tid >> 4;
    const int m0 = blockIdx.y * 64;
    const int n0 = blockIdx.x * 64;

    const int lm  = tid >> 2;
    const int lk4 = (tid & 3) * 4;
    const int bk  = tid >> 4;
    const int bn4 = (tid & 15) * 4;

    float acc[4][4] = {};

    for (int kb = 0; kb < DD; kb += 16) {
        float4 av = *(const float4*)(X + (size_t)(m0 + lm) * DD + kb + lk4);
        As[lk4 + 0][lm] = av.x;
        As[lk4 + 1][lm] = av.y;
        As[lk4 + 2][lm] = av.z;
        As[lk4 + 3][lm] = av.w;
        *(float4*)&Bs[bk][bn4] =
            *(const float4*)(W + (size_t)(kb + bk) * DD + n0 + bn4);
        __syncthreads();
#pragma unroll
        for (int k = 0; k < 16; ++k) {
            float4 a = *(const float4*)&As[k][ty * 4];
            float4 b = *(const float4*)&Bs[k][tx * 4];
            float aa[4] = {a.x, a.y, a.z, a.w};
            float bb[4] = {b.x, b.y, b.z, b.w};
#pragma unroll
            for (int i = 0; i < 4; ++i)
#pragma unroll
                for (int j = 0; j < 4; ++j) acc[i][j] += aa[i] * bb[j];
        }
        __syncthreads();
    }
#pragma unroll
    for (int i = 0; i < 4; ++i) {
        int row = m0 + ty * 4 + i;
        int col = n0 + tx * 4;
        u16x4 hi, lo;
        float v0 = acc[i][0], v1 = acc[i][1], v2 = acc[i][2], v3 = acc[i][3];
        hi.x = f2bf(v0); lo.x = f2bf(v0 - bf2f(hi.x));
        hi.y = f2bf(v1); lo.y = f2bf(v1 - bf2f(hi.y));
        hi.z = f2bf(v2); lo.z = f2bf(v2 - bf2f(hi.z));
        hi.w = f2bf(v3); lo.w = f2bf(v3 - bf2f(hi.w));
        if (MODE == 0) {
            *(u16x4*)(qpack + (size_t)row * 4096 + col * 2)        = hi;
            *(u16x4*)(qpack + (size_t)row * 4096 + 2048 + col * 2) = lo;
        } else {
            *(u16x4*)(khi + (size_t)row * 1024 + col) = hi;
            *(u16x4*)(klo + (size_t)row * 1024 + col) = lo;
        }
    }
}

// ---------------------------------------------------------------------------
// X^T bf16: XT[1024][8192] = bf16(X)^T  (PV B-operand layout)
// ---------------------------------------------------------------------------
__global__ __launch_bounds__(256) void prep_xt(const float* __restrict__ X,
                                               unsigned short* __restrict__ XT) {
    __shared__ float t[64][65];
    const int r0 = blockIdx.x * 64;   // X row tile
    const int c0 = blockIdx.y * 64;   // X col (feature) tile
    const int tid = threadIdx.x;
    const int tr = tid >> 6;          // 0..3
    const int tc = tid & 63;
#pragma unroll
    for (int rep = 0; rep < 16; ++rep) {
        int r = rep * 4 + tr;
        t[r][tc] = X[(size_t)(r0 + r) * DD + c0 + tc];
    }
    __syncthreads();
#pragma unroll
    for (int rep = 0; rep < 16; ++rep) {
        int c = rep * 4 + tr;         // feature within tile
        XT[(size_t)(c0 + c) * NR + r0 + tc] = f2bf(t[tc][c]);
    }
}

// ---------------------------------------------------------------------------
// Fused flash attention via split-bf16 MFMA.
// Block: 32 q-rows, 512 threads = 8 waves (1x8 over 512-col K tiles).
// S = (Qh+Ql)(Kh+Kl)^T via 3 MFMA products; online softmax; O += P·X via MFMA.
// Q staged in LDS (XOR-swizzled); K/XT fragments read direct from global (L2).
// ---------------------------------------------------------------------------
__global__ __launch_bounds__(512, 2) void flash_mfma(
        const char* qpk, const unsigned short* __restrict__ Khi,
        const unsigned short* __restrict__ Klo,
        const unsigned short* __restrict__ XT, float* outp) {
    __shared__ __align__(128) char lds[131072];   // QsHi[32][2KB] | QsLo[32][2KB]; Ps aliases last 32KB
    __shared__ __align__(16) float smax[32][8];
    __shared__ __align__(16) float ssum[32][8];

    const int tid = threadIdx.x;
    const int l   = tid & 63;
    const int w   = tid >> 6;
    const int l15 = l & 15;
    const int lk  = l >> 4;
    const int q0  = blockIdx.x * 32;

    f32x4 o[2][8];
    float m_run[2][4], l_run[2][4];
#pragma unroll
    for (int mr = 0; mr < 2; ++mr) {
#pragma unroll
        for (int nf = 0; nf < 8; ++nf) o[mr][nf] = f32x4{0.f, 0.f, 0.f, 0.f};
#pragma unroll
        for (int g = 0; g < 4; ++g) { m_run[mr][g] = -3.0e38f; l_run[mr][g] = 0.f; }
    }

    for (int k0 = 0; k0 < NR; k0 += 512) {
        __syncthreads();   // prior PV done with Ps (aliases Qs region)
        // ---- stage Q hi/lo into LDS, XOR-swizzled 16B slots ----
#pragma unroll
        for (int rep = 0; rep < 16; ++rep) {
            int s   = rep * 512 + tid;    // 16B slot id, 8192 total
            int arr = s >> 12;            // 0 = hi, 1 = lo
            int r   = (s >> 7) & 31;
            int j   = s & 127;
            const char* src = qpk + (size_t)(q0 + r) * 4096 + arr * 2048 + j * 16;
            bf16x8 v = *(const bf16x8*)src;
            *(bf16x8*)&lds[arr * 65536 + r * 2048 + ((j ^ (r & 7)) << 4)] = v;
        }
        __syncthreads();

        // ---- S tile: acc[mr][nf] over D=1024 in 32-steps ----
        f32x4 acc[2][4];
#pragma unroll
        for (int mr = 0; mr < 2; ++mr)
#pragma unroll
            for (int nf = 0; nf < 4; ++nf) acc[mr][nf] = f32x4{0.f, 0.f, 0.f, 0.f};

        for (int ks = 0; ks < 32; ++ks) {
            const int slot = ks * 4 + lk;
            bf16x8 ah[2], al[2];
#pragma unroll
            for (int mr = 0; mr < 2; ++mr) {
                int r = mr * 16 + l15;
                int off = r * 2048 + ((slot ^ (r & 7)) << 4);
                ah[mr] = *(const bf16x8*)&lds[off];
                al[mr] = *(const bf16x8*)&lds[65536 + off];
            }
            bf16x8 bh[4], bl[4];
#pragma unroll
            for (int nf = 0; nf < 4; ++nf) {
                size_t off = (size_t)(k0 + w * 64 + nf * 16 + l15) * 1024 + ks * 32 + lk * 8;
                bh[nf] = *(const bf16x8*)(Khi + off);
                bl[nf] = *(const bf16x8*)(Klo + off);
            }
#pragma unroll
            for (int mr = 0; mr < 2; ++mr)
#pragma unroll
                for (int nf = 0; nf < 4; ++nf) {
                    acc[mr][nf] = __builtin_amdgcn_mfma_f32_16x16x32_bf16(ah[mr], bh[nf], acc[mr][nf], 0, 0, 0);
                    acc[mr][nf] = __builtin_amdgcn_mfma_f32_16x16x32_bf16(al[mr], bh[nf], acc[mr][nf], 0, 0, 0);
                    acc[mr][nf] = __builtin_amdgcn_mfma_f32_16x16x32_bf16(ah[mr], bl[nf], acc[mr][nf], 0, 0, 0);
                }
        }

#pragma unroll
        for (int mr = 0; mr < 2; ++mr)
#pragma unroll
            for (int nf = 0; nf < 4; ++nf) acc[mr][nf] *= 0.03125f;   // 1/sqrt(1024)

        // ---- block-wide row max (in-lane -> 16-lane shfl -> cross-wave LDS) ----
        float mx[2][4];
#pragma unroll
        for (int mr = 0; mr < 2; ++mr)
#pragma unroll
            for (int g = 0; g < 4; ++g) {
                float m = fmaxf(fmaxf(acc[mr][0][g], acc[mr][1][g]),
                                fmaxf(acc[mr][2][g], acc[mr][3][g]));
#pragma unroll
                for (int msk = 1; msk <= 8; msk <<= 1)
                    m = fmaxf(m, __shfl_xor(m, msk, 64));
                mx[mr][g] = m;
            }
        if (l15 == 0) {
#pragma unroll
            for (int mr = 0; mr < 2; ++mr)
#pragma unroll
                for (int g = 0; g < 4; ++g) smax[mr * 16 + lk * 4 + g][w] = mx[mr][g];
        }
        __syncthreads();

        float m_new[2][4], corr[2][4];
#pragma unroll
        for (int mr = 0; mr < 2; ++mr)
#pragma unroll
            for (int g = 0; g < 4; ++g) {
                int r = mr * 16 + lk * 4 + g;
                float4 v0 = *(const float4*)&smax[r][0];
                float4 v1 = *(const float4*)&smax[r][4];
                float mn = fmaxf(fmaxf(fmaxf(v0.x, v0.y), fmaxf(v0.z, v0.w)),
                                 fmaxf(fmaxf(v1.x, v1.y), fmaxf(v1.z, v1.w)));
                mn = fmaxf(mn, m_run[mr][g]);
                m_new[mr][g] = mn;
                corr[mr][g]  = __expf(m_run[mr][g] - mn);
            }

        // ---- p = exp(s - m), write Ps (bf16, swizzled), partial sums ----
        float psum[2][4] = {};
#pragma unroll
        for (int mr = 0; mr < 2; ++mr)
#pragma unroll
            for (int nf = 0; nf < 4; ++nf)
#pragma unroll
                for (int g = 0; g < 4; ++g) {
                    int r = mr * 16 + lk * 4 + g;
                    float p = __expf(acc[mr][nf][g] - m_new[mr][g]);
                    psum[mr][g] += p;
                    int colL = w * 64 + nf * 16 + l15;
                    int off = r * 1024 + (((colL >> 3) ^ (r & 7)) << 4) + (colL & 7) * 2;
                    *(unsigned short*)&lds[98304 + off] = f2bf(p);
                }
#pragma unroll
        for (int mr = 0; mr < 2; ++mr)
#pragma unroll
            for (int g = 0; g < 4; ++g) {
                float sm = psum[mr][g];
#pragma unroll
                for (int msk = 1; msk <= 8; msk <<= 1) sm += __shfl_xor(sm, msk, 64);
                if (l15 == 0) ssum[mr * 16 + lk * 4 + g][w] = sm;
            }
        __syncthreads();

#pragma unroll
        for (int mr = 0; mr < 2; ++mr)
#pragma unroll
            for (int g = 0; g < 4; ++g) {
                int r = mr * 16 + lk * 4 + g;
                float4 v0 = *(const float4*)&ssum[r][0];
                float4 v1 = *(const float4*)&ssum[r][4];
                float lt = v0.x + v0.y + v0.z + v0.w + v1.x + v1.y + v1.z + v1.w;
                l_run[mr][g] = l_run[mr][g] * corr[mr][g] + lt;
                m_run[mr][g] = m_new[mr][g];
            }
#pragma unroll
        for (int mr = 0; mr < 2; ++mr)
#pragma unroll
            for (int nf = 0; nf < 8; ++nf)
#pragma unroll
                for (int g = 0; g < 4; ++g) o[mr][nf][g] *= corr[mr][g];

        // ---- O += P · X  (P from LDS, X^T fragments direct from global) ----
        for (int ks2 = 0; ks2 < 16; ++ks2) {
            const int slot = ks2 * 4 + lk;
            bf16x8 pa[2];
#pragma unroll
            for (int mr = 0; mr < 2; ++mr) {
                int r = mr * 16 + l15;
                pa[mr] = *(const bf16x8*)&lds[98304 + r * 1024 + ((slot ^ (r & 7)) << 4)];
            }
            bf16x8 xb[8];
#pragma unroll
            for (int nf = 0; nf < 8; ++nf) {
                size_t off = (size_t)(w * 128 + nf * 16 + l15) * NR + k0 + ks2 * 32 + lk * 8;
                xb[nf] = *(const bf16x8*)(XT + off);
            }
#pragma unroll
            for (int mr = 0; mr < 2; ++mr)
#pragma unroll
                for (int nf = 0; nf < 8; ++nf)
                    o[mr][nf] = __builtin_amdgcn_mfma_f32_16x16x32_bf16(pa[mr], xb[nf], o[mr][nf], 0, 0, 0);
        }
    }

    // ---- epilogue: normalize, store (overwrites this block's own Q records) ----
#pragma unroll
    for (int mr = 0; mr < 2; ++mr)
#pragma unroll
        for (int g = 0; g < 4; ++g) {
            int r = q0 + mr * 16 + lk * 4 + g;
            float inv = 1.0f / l_run[mr][g];
#pragma unroll
            for (int nf = 0; nf < 8; ++nf)
                outp[(size_t)r * 1024 + w * 128 + nf * 16 + l15] = o[mr][nf][g] * inv;
        }
}

extern "C" void kernel_launch(void* const* d_in, const int* in_sizes, int n_in,
                              void* d_out, int out_size, void* d_ws, size_t ws_size,
                              hipStream_t stream) {
    const float* X  = (const float*)d_in[0];
    const float* Wq = (const float*)d_in[1];
    const float* Wk = (const float*)d_in[2];

    char* qpack = (char*)d_out;                       // per-row [Qhi|Qlo] records, 4KB/row
    unsigned short* khi = (unsigned short*)d_ws;      // 16 MiB
    unsigned short* klo = khi + (size_t)NR * DD;      // 16 MiB
    unsigned short* xt  = klo + (size_t)NR * DD;      // 16 MiB  (XT[1024][8192])

    dim3 pgrid(DD / 64, NR / 64);                     // (16, 128)
    proj_gemm<0><<<pgrid, 256, 0, stream>>>(X, Wq, qpack, nullptr, nullptr);
    proj_gemm<1><<<pgrid, 256, 0, stream>>>(X, Wk, nullptr, khi, klo);
    prep_xt<<<dim3(NR / 64, DD / 64), 256, 0, stream>>>(X, xt);

    flash_mfma<<<NR / 32, 512, 0, stream>>>(qpack, khi, klo, xt, (float*)d_out);
}

// Round 3
// 1753.573 us; speedup vs baseline: 3.4221x; 1.2161x over previous
//
#include <hip/hip_runtime.h>
#include <hip/hip_bf16.h>
#include <math.h>

#define NR 8192
#define DD 1024

typedef __attribute__((ext_vector_type(8))) short bf16x8;
typedef __attribute__((ext_vector_type(4))) float f32x4;
typedef unsigned short ushort_t;

struct u16x4 { unsigned short x, y, z, w; };

__device__ __forceinline__ unsigned short f2bf(float v) {
    __hip_bfloat16 h = __float2bfloat16(v);
    return *(unsigned short*)&h;
}
__device__ __forceinline__ float bf2f(unsigned short u) {
    __hip_bfloat16 h = *(__hip_bfloat16*)&u;
    return __bfloat162float(h);
}

// ---------------------------------------------------------------------------
// Projection GEMM (fp32, known-good from R1/R2).
// MODE 0: pack per-row records [hi(2048B)|lo(2048B)] into qpack (d_out).
// MODE 1: write khi/klo bf16 arrays (ws).
// ---------------------------------------------------------------------------
template <int MODE>
__global__ __launch_bounds__(256) void proj_gemm(const float* __restrict__ X,
                                                 const float* __restrict__ W,
                                                 char* qpack,
                                                 unsigned short* khi,
                                                 unsigned short* klo) {
    __shared__ float As[16][64];
    __shared__ float Bs[16][64];

    const int tid = threadIdx.x;
    const int tx = tid & 15;
    const int ty = tid >> 4;
    const int m0 = blockIdx.y * 64;
    const int n0 = blockIdx.x * 64;

    const int lm  = tid >> 2;
    const int lk4 = (tid & 3) * 4;
    const int bk  = tid >> 4;
    const int bn4 = (tid & 15) * 4;

    float acc[4][4] = {};

    for (int kb = 0; kb < DD; kb += 16) {
        float4 av = *(const float4*)(X + (size_t)(m0 + lm) * DD + kb + lk4);
        As[lk4 + 0][lm] = av.x;
        As[lk4 + 1][lm] = av.y;
        As[lk4 + 2][lm] = av.z;
        As[lk4 + 3][lm] = av.w;
        *(float4*)&Bs[bk][bn4] =
            *(const float4*)(W + (size_t)(kb + bk) * DD + n0 + bn4);
        __syncthreads();
#pragma unroll
        for (int k = 0; k < 16; ++k) {
            float4 a = *(const float4*)&As[k][ty * 4];
            float4 b = *(const float4*)&Bs[k][tx * 4];
            float aa[4] = {a.x, a.y, a.z, a.w};
            float bb[4] = {b.x, b.y, b.z, b.w};
#pragma unroll
            for (int i = 0; i < 4; ++i)
#pragma unroll
                for (int j = 0; j < 4; ++j) acc[i][j] += aa[i] * bb[j];
        }
        __syncthreads();
    }
#pragma unroll
    for (int i = 0; i < 4; ++i) {
        int row = m0 + ty * 4 + i;
        int col = n0 + tx * 4;
        u16x4 hi, lo;
        float v0 = acc[i][0], v1 = acc[i][1], v2 = acc[i][2], v3 = acc[i][3];
        hi.x = f2bf(v0); lo.x = f2bf(v0 - bf2f(hi.x));
        hi.y = f2bf(v1); lo.y = f2bf(v1 - bf2f(hi.y));
        hi.z = f2bf(v2); lo.z = f2bf(v2 - bf2f(hi.z));
        hi.w = f2bf(v3); lo.w = f2bf(v3 - bf2f(hi.w));
        if (MODE == 0) {
            *(u16x4*)(qpack + (size_t)row * 4096 + col * 2)        = hi;
            *(u16x4*)(qpack + (size_t)row * 4096 + 2048 + col * 2) = lo;
        } else {
            *(u16x4*)(khi + (size_t)row * 1024 + col) = hi;
            *(u16x4*)(klo + (size_t)row * 1024 + col) = lo;
        }
    }
}

// ---------------------------------------------------------------------------
// X^T bf16: XT[1024][8192] = bf16(X)^T  (PV B-operand layout)
// ---------------------------------------------------------------------------
__global__ __launch_bounds__(256) void prep_xt(const float* __restrict__ X,
                                               unsigned short* __restrict__ XT) {
    __shared__ float t[64][65];
    const int r0 = blockIdx.x * 64;
    const int c0 = blockIdx.y * 64;
    const int tid = threadIdx.x;
    const int tr = tid >> 6;
    const int tc = tid & 63;
#pragma unroll
    for (int rep = 0; rep < 16; ++rep) {
        int r = rep * 4 + tr;
        t[r][tc] = X[(size_t)(r0 + r) * DD + c0 + tc];
    }
    __syncthreads();
#pragma unroll
    for (int rep = 0; rep < 16; ++rep) {
        int c = rep * 4 + tr;
        XT[(size_t)(c0 + c) * NR + r0 + tc] = f2bf(t[tc][c]);
    }
}

// ---------------------------------------------------------------------------
// Flash attention v2: BM=64 q-rows, BN=256 kv-tile, 512 thr = 8 waves (1x8).
// SPLIT: grid 256 = 128 qb x 2 kv-halves; writes normalized-bf16 partial O +
//        (m,l) to ws; combine kernel merges.  !SPLIT: grid 128, direct store.
// Wave w covers S cols w*32..+31 (nf=2) and O cols w*128..+127 (nf=8).
// Lane rows: r = mr*16 + (l>>4)*4 + g  (mr<4, g<4); 16 col-lanes l15.
// ---------------------------------------------------------------------------
template <bool SPLIT>
__global__ __launch_bounds__(512, 2) void flash2(
        const char* __restrict__ qpk,
        const unsigned short* __restrict__ Khi,
        const unsigned short* __restrict__ Klo,
        const unsigned short* __restrict__ XT,
        float* __restrict__ outp,
        unsigned short* __restrict__ On,
        float* __restrict__ mlbuf) {
    __shared__ __align__(128) char qlds[65536];   // Q chunk: hi[64][512B] | lo
    __shared__ __align__(128) char plds[32768];   // P: [64][512B] bf16
    __shared__ __align__(16) float smax[64][8];
    __shared__ __align__(16) float ssum[64][8];

    const int tid = threadIdx.x;
    const int l   = tid & 63;
    const int w   = tid >> 6;
    const int l15 = l & 15;
    const int lk  = l >> 4;

    int qb, sp;
    if (SPLIT) { qb = blockIdx.x >> 1; sp = blockIdx.x & 1; }
    else       { qb = blockIdx.x;      sp = 0; }
    const int q0  = qb * 64;
    const int kv0 = SPLIT ? sp * (NR / 2) : 0;
    const int kv1 = SPLIT ? kv0 + (NR / 2) : NR;

    f32x4 o[4][8];
    float m_run[4][4], l_run[4][4];
#pragma unroll
    for (int mr = 0; mr < 4; ++mr) {
#pragma unroll
        for (int nf = 0; nf < 8; ++nf) o[mr][nf] = f32x4{0.f, 0.f, 0.f, 0.f};
#pragma unroll
        for (int g = 0; g < 4; ++g) { m_run[mr][g] = -3.0e38f; l_run[mr][g] = 0.f; }
    }

    for (int k0 = kv0; k0 < kv1; k0 += 256) {
        // ---- S = Q.K^T over D in 256-chunks ----
        f32x4 acc[4][2];
#pragma unroll
        for (int mr = 0; mr < 4; ++mr)
#pragma unroll
            for (int nf = 0; nf < 2; ++nf) acc[mr][nf] = f32x4{0.f, 0.f, 0.f, 0.f};

        for (int kc = 0; kc < DD; kc += 256) {
            __syncthreads();   // prior readers of qlds done
            // stage Q chunk hi/lo: 4096 16B-slots / 512 thr = 8 each
#pragma unroll
            for (int rep = 0; rep < 8; ++rep) {
                int s   = rep * 512 + tid;
                int arr = s >> 11;            // 0 hi, 1 lo
                int r   = (s >> 5) & 63;
                int j   = s & 31;
                bf16x8 v = *(const bf16x8*)(qpk + (size_t)(q0 + r) * 4096 +
                                            arr * 2048 + kc * 2 + j * 16);
                *(bf16x8*)&qlds[arr * 32768 + r * 512 + ((j ^ (r & 7)) << 4)] = v;
            }
            __syncthreads();

#pragma unroll
            for (int ks = 0; ks < 8; ++ks) {
                const int slot = ks * 4 + lk;
                bf16x8 ah[4], al[4];
#pragma unroll
                for (int mr = 0; mr < 4; ++mr) {
                    int r = mr * 16 + l15;
                    int off = r * 512 + ((slot ^ (r & 7)) << 4);
                    ah[mr] = *(const bf16x8*)&qlds[off];
                    al[mr] = *(const bf16x8*)&qlds[32768 + off];
                }
                bf16x8 bh[2], bl[2];
#pragma unroll
                for (int nf = 0; nf < 2; ++nf) {
                    size_t off = (size_t)(k0 + w * 32 + nf * 16 + l15) * 1024 +
                                 kc + ks * 32 + lk * 8;
                    bh[nf] = *(const bf16x8*)(Khi + off);
                    bl[nf] = *(const bf16x8*)(Klo + off);
                }
#pragma unroll
                for (int mr = 0; mr < 4; ++mr)
#pragma unroll
                    for (int nf = 0; nf < 2; ++nf) {
                        acc[mr][nf] = __builtin_amdgcn_mfma_f32_16x16x32_bf16(ah[mr], bh[nf], acc[mr][nf], 0, 0, 0);
                        acc[mr][nf] = __builtin_amdgcn_mfma_f32_16x16x32_bf16(al[mr], bh[nf], acc[mr][nf], 0, 0, 0);
                        acc[mr][nf] = __builtin_amdgcn_mfma_f32_16x16x32_bf16(ah[mr], bl[nf], acc[mr][nf], 0, 0, 0);
                    }
            }
        }

#pragma unroll
        for (int mr = 0; mr < 4; ++mr)
#pragma unroll
            for (int nf = 0; nf < 2; ++nf) acc[mr][nf] *= 0.03125f;

        // ---- row max: in-lane -> 16-lane shfl -> cross-wave LDS ----
#pragma unroll
        for (int mr = 0; mr < 4; ++mr)
#pragma unroll
            for (int g = 0; g < 4; ++g) {
                float m = fmaxf(acc[mr][0][g], acc[mr][1][g]);
#pragma unroll
                for (int msk = 1; msk <= 8; msk <<= 1)
                    m = fmaxf(m, __shfl_xor(m, msk, 64));
                if (l15 == 0) smax[mr * 16 + lk * 4 + g][w] = m;
            }
        __syncthreads();

        float m_new[4][4], corr[4][4], psum[4][4];
#pragma unroll
        for (int mr = 0; mr < 4; ++mr)
#pragma unroll
            for (int g = 0; g < 4; ++g) {
                int r = mr * 16 + lk * 4 + g;
                float4 v0 = *(const float4*)&smax[r][0];
                float4 v1 = *(const float4*)&smax[r][4];
                float mn = fmaxf(fmaxf(fmaxf(v0.x, v0.y), fmaxf(v0.z, v0.w)),
                                 fmaxf(fmaxf(v1.x, v1.y), fmaxf(v1.z, v1.w)));
                mn = fmaxf(mn, m_run[mr][g]);
                m_new[mr][g] = mn;
                corr[mr][g]  = __expf(m_run[mr][g] - mn);
                psum[mr][g]  = 0.f;
            }

        // p = exp(s - m): write Ps (bf16, swizzled 16B slots within 8-group)
#pragma unroll
        for (int mr = 0; mr < 4; ++mr)
#pragma unroll
            for (int nf = 0; nf < 2; ++nf)
#pragma unroll
                for (int g = 0; g < 4; ++g) {
                    int r = mr * 16 + lk * 4 + g;
                    float p = __expf(acc[mr][nf][g] - m_new[mr][g]);
                    psum[mr][g] += p;
                    int colL = w * 32 + nf * 16 + l15;
                    int off = r * 512 + ((((colL >> 3) ^ (r & 7))) << 4) + (colL & 7) * 2;
                    *(unsigned short*)&plds[off] = f2bf(p);
                }
#pragma unroll
        for (int mr = 0; mr < 4; ++mr)
#pragma unroll
            for (int g = 0; g < 4; ++g) {
                float sm = psum[mr][g];
#pragma unroll
                for (int msk = 1; msk <= 8; msk <<= 1) sm += __shfl_xor(sm, msk, 64);
                if (l15 == 0) ssum[mr * 16 + lk * 4 + g][w] = sm;
            }
        __syncthreads();

#pragma unroll
        for (int mr = 0; mr < 4; ++mr)
#pragma unroll
            for (int g = 0; g < 4; ++g) {
                int r = mr * 16 + lk * 4 + g;
                float4 v0 = *(const float4*)&ssum[r][0];
                float4 v1 = *(const float4*)&ssum[r][4];
                float lt = v0.x + v0.y + v0.z + v0.w + v1.x + v1.y + v1.z + v1.w;
                l_run[mr][g] = l_run[mr][g] * corr[mr][g] + lt;
                m_run[mr][g] = m_new[mr][g];
            }
#pragma unroll
        for (int mr = 0; mr < 4; ++mr)
#pragma unroll
            for (int nf = 0; nf < 8; ++nf)
#pragma unroll
                for (int g = 0; g < 4; ++g) o[mr][nf][g] *= corr[mr][g];

        // ---- O += P . X  (P from LDS, X^T direct from global) ----
#pragma unroll
        for (int ks2 = 0; ks2 < 8; ++ks2) {
            const int slot = ks2 * 4 + lk;
            bf16x8 pa[4];
#pragma unroll
            for (int mr = 0; mr < 4; ++mr) {
                int r = mr * 16 + l15;
                pa[mr] = *(const bf16x8*)&plds[r * 512 + ((slot ^ (r & 7)) << 4)];
            }
            bf16x8 xb[8];
#pragma unroll
            for (int nf = 0; nf < 8; ++nf) {
                size_t off = (size_t)(w * 128 + nf * 16 + l15) * NR +
                             k0 + ks2 * 32 + lk * 8;
                xb[nf] = *(const bf16x8*)(XT + off);
            }
#pragma unroll
            for (int mr = 0; mr < 4; ++mr)
#pragma unroll
                for (int nf = 0; nf < 8; ++nf)
                    o[mr][nf] = __builtin_amdgcn_mfma_f32_16x16x32_bf16(pa[mr], xb[nf], o[mr][nf], 0, 0, 0);
        }
    }

    // ---- epilogue ----
    if (SPLIT) {
#pragma unroll
        for (int mr = 0; mr < 4; ++mr)
#pragma unroll
            for (int g = 0; g < 4; ++g) {
                int r = mr * 16 + lk * 4 + g;
                float inv = 1.0f / l_run[mr][g];
#pragma unroll
                for (int nf = 0; nf < 8; ++nf)
                    On[(size_t)sp * NR * DD + (size_t)(q0 + r) * DD +
                       w * 128 + nf * 16 + l15] = f2bf(o[mr][nf][g] * inv);
                if (w == 0 && l15 == 0) {
                    mlbuf[(size_t)sp * NR + q0 + r]          = m_run[mr][g];
                    mlbuf[2 * NR + (size_t)sp * NR + q0 + r] = l_run[mr][g];
                }
            }
    } else {
#pragma unroll
        for (int mr = 0; mr < 4; ++mr)
#pragma unroll
            for (int g = 0; g < 4; ++g) {
                int r = q0 + mr * 16 + lk * 4 + g;
                float inv = 1.0f / l_run[mr][g];
#pragma unroll
                for (int nf = 0; nf < 8; ++nf)
                    outp[(size_t)r * DD + w * 128 + nf * 16 + l15] = o[mr][nf][g] * inv;
            }
    }
}

// ---------------------------------------------------------------------------
// Combine the two KV-split partials:  out = sum_i w_i * O_i_norm
// ---------------------------------------------------------------------------
__global__ __launch_bounds__(256) void combine2(const unsigned short* __restrict__ On,
                                                const float* __restrict__ mlbuf,
                                                float* __restrict__ outp) {
    const int r = blockIdx.x;
    float m1 = mlbuf[r],          m2 = mlbuf[NR + r];
    float l1 = mlbuf[2 * NR + r], l2 = mlbuf[3 * NR + r];
    float m  = fmaxf(m1, m2);
    float w1 = l1 * __expf(m1 - m);
    float w2 = l2 * __expf(m2 - m);
    float inv = 1.0f / (w1 + w2);
    w1 *= inv; w2 *= inv;
    const int d = threadIdx.x * 4;
    u16x4 a = *(const u16x4*)(On + (size_t)r * DD + d);
    u16x4 b = *(const u16x4*)(On + (size_t)NR * DD + (size_t)r * DD + d);
    float4 v;
    v.x = w1 * bf2f(a.x) + w2 * bf2f(b.x);
    v.y = w1 * bf2f(a.y) + w2 * bf2f(b.y);
    v.z = w1 * bf2f(a.z) + w2 * bf2f(b.z);
    v.w = w1 * bf2f(a.w) + w2 * bf2f(b.w);
    *(float4*)(outp + (size_t)r * DD + d) = v;
}

extern "C" void kernel_launch(void* const* d_in, const int* in_sizes, int n_in,
                              void* d_out, int out_size, void* d_ws, size_t ws_size,
                              hipStream_t stream) {
    const float* X  = (const float*)d_in[0];
    const float* Wq = (const float*)d_in[1];
    const float* Wk = (const float*)d_in[2];

    char* qpack = (char*)d_out;                        // [Qhi|Qlo] 4KB/row
    unsigned short* khi = (unsigned short*)d_ws;       // 16 MiB
    unsigned short* klo = khi + (size_t)NR * DD;       // 16 MiB
    unsigned short* xt  = klo + (size_t)NR * DD;       // 16 MiB
    unsigned short* On  = xt + (size_t)DD * NR;        // 32 MiB (2 splits)
    float* mlbuf        = (float*)(On + (size_t)2 * NR * DD);  // 128 KiB

    const size_t need_split = (size_t)NR * DD * 2 * 3 * 2   // khi,klo,xt
                            + (size_t)2 * NR * DD * 2       // On
                            + (size_t)4 * NR * 4;           // mlbuf

    dim3 pgrid(DD / 64, NR / 64);
    proj_gemm<0><<<pgrid, 256, 0, stream>>>(X, Wq, qpack, nullptr, nullptr);
    proj_gemm<1><<<pgrid, 256, 0, stream>>>(X, Wk, nullptr, khi, klo);
    prep_xt<<<dim3(NR / 64, DD / 64), 256, 0, stream>>>(X, xt);

    if (ws_size >= need_split) {
        flash2<true><<<NR / 64 * 2, 512, 0, stream>>>(qpack, khi, klo, xt,
                                                      nullptr, On, mlbuf);
        combine2<<<NR, 256, 0, stream>>>(On, mlbuf, (float*)d_out);
    } else {
        flash2<false><<<NR / 64, 512, 0, stream>>>(qpack, khi, klo, xt,
                                                   (float*)d_out, nullptr, nullptr);
    }
}